// Round 5
// baseline (94.439 us; speedup 1.0000x reference)
//
#include <hip/hip_runtime.h>

typedef unsigned int uint32;
typedef unsigned short ushort;

typedef __bf16  bf16x8   __attribute__((ext_vector_type(8)));
typedef float   f32x4    __attribute__((ext_vector_type(4)));
typedef ushort  ushort4v __attribute__((ext_vector_type(4)));

#define K_CODES 1024
#define CDIM    64
#define HWALL   4096      // H*W
#define CHW     262144    // CDIM*HWALL
#define ROWS    128       // z-rows per tile (2 tiles per block)

__device__ __forceinline__ ushort f2bf(float f) {
    uint32 u = __builtin_bit_cast(uint32, f);
    u += 0x7FFFu + ((u >> 16) & 1u);   // RNE
    return (ushort)(u >> 16);
}

// Single persistent kernel: 256 blocks (1/CU) x 1024 threads (16 waves).
// LDS: full bf16 codebook (128 KB, chunk-swizzled: chunk j of code k at slot
// (j+k)&7) staged ONCE per CU with inline fp32->bf16 conversion + per-thread
// exact negbias. Two 128-row z-tiles per block; tile-1 z loads are issued
// before the first barrier and land in registers during gemm0 (latency hidden).
__global__ __launch_bounds__(1024, 4) void vq_kernel(const float* __restrict__ z,
                                                     const float* __restrict__ cb,
                                                     float* __restrict__ out) {
    __shared__ __align__(16) ushort cbL[K_CODES * 64];   // 128 KB swizzled codebook
    __shared__ __align__(16) ushort Abf[ROWS * 72];      // 18 KB A-tile, pitch 72
    __shared__ float nbL[K_CODES];                       // 4 KB
    __shared__ float partial[8][ROWS];                   // 4 KB packed argmax keys
    __shared__ float loss_acc;                           // total 157700 B <= 160 KiB

    const int t   = threadIdx.x;
    const int blk = blockIdx.x;
    const int b   = blk >> 4;
    const int hw0 = (blk & 15) << 8;          // 256 rows per block
    const int zoff0 = b * CHW + hw0;

    if (t == 0) loss_acc = 0.f;

    const int r  = t & 127;    // z-row within tile (lanes consecutive -> coalesced)
    const int cg = t >> 7;     // c-group 0..7

    // ---- issue tile-0 z loads first (deepest dependency) ----
    float z0v[8];
    #pragma unroll
    for (int j = 0; j < 8; ++j) z0v[j] = z[zoff0 + (cg * 8 + j) * HWALL + r];

    // ---- codebook: fp32 -> bf16, swizzled into LDS; exact fp32 negbias ----
    // thread t owns code k = t (reads 256 B; L2-resident after first touch)
    {
        const f32x4* cbv = (const f32x4*)(cb + t * 64);
        float ssum = 0.f;
        #pragma unroll
        for (int j = 0; j < 8; ++j) {          // chunk j = elements 8j..8j+7
            f32x4 lo = cbv[2 * j], hi = cbv[2 * j + 1];
            ushort4v p0, p1;
            #pragma unroll
            for (int e = 0; e < 4; ++e) {
                p0[e] = f2bf(lo[e]);  p1[e] = f2bf(hi[e]);
                ssum += lo[e] * lo[e] + hi[e] * hi[e];
            }
            int slot = (j + t) & 7;
            *(ushort4v*)&cbL[(t << 6) + (slot << 3)]     = p0;
            *(ushort4v*)&cbL[(t << 6) + (slot << 3) + 4] = p1;
        }
        nbL[t] = -0.5f * ssum;
    }

    // ---- tile-0 z -> Abf (bf16, pitch 72) ----
    {
        ushort4v pk0, pk1;
        #pragma unroll
        for (int j = 0; j < 4; ++j) { pk0[j] = f2bf(z0v[j]); pk1[j] = f2bf(z0v[4 + j]); }
        *(ushort4v*)&Abf[r * 72 + cg * 8]     = pk0;
        *(ushort4v*)&Abf[r * 72 + cg * 8 + 4] = pk1;
    }

    // ---- issue tile-1 z loads now; they arrive during gemm0 ----
    float z1v[8];
    #pragma unroll
    for (int j = 0; j < 8; ++j) z1v[j] = z[zoff0 + 128 + (cg * 8 + j) * HWALL + r];

    __syncthreads();

    // wave tiling: 16 waves = 2 m-groups x 8 n-groups
    const int w  = t >> 6;
    const int l  = t & 63;
    const int mg = w & 1;      // rows [mg*64, +64)
    const int ng = w >> 1;     // n-tiles [ng*8, +8)
    const int m  = l & 15;
    const int q  = l >> 4;

    int zoffT = zoff0;
    #pragma unroll 1
    for (int T = 0; T < 2; ++T) {
        // ---- gemm: B + negbias from LDS, packed-key argmax ----
        bf16x8 a[4][2];
        #pragma unroll
        for (int mb = 0; mb < 4; ++mb) {
            int row = mg * 64 + mb * 16 + m;
            #pragma unroll
            for (int ks = 0; ks < 2; ++ks)
                a[mb][ks] = *(const bf16x8*)&Abf[row * 72 + ks * 32 + q * 8];
        }

        float best[16];
        #pragma unroll
        for (int i = 0; i < 16; ++i) best[i] = -__builtin_inff();

        #pragma unroll 2
        for (int ntl = 0; ntl < 8; ++ntl) {
            int nt  = ng * 8 + ntl;
            int col = (nt << 4) + m;
            int e0  = (col << 6) + (((q + col) & 7) << 3);   // swizzled chunk q
            bf16x8 b0 = *(const bf16x8*)&cbL[e0];
            bf16x8 b1 = *(const bf16x8*)&cbL[e0 ^ 32];       // chunk q+4
            float  nb = nbL[col];

            uint32 tag = 1023u - (uint32)col;
            f32x4 acc0;
            acc0[0] = nb; acc0[1] = nb; acc0[2] = nb; acc0[3] = nb;
            #pragma unroll
            for (int mb = 0; mb < 4; ++mb) {
                f32x4 acc = __builtin_amdgcn_mfma_f32_16x16x32_bf16(a[mb][0], b0, acc0, 0, 0, 0);
                acc       = __builtin_amdgcn_mfma_f32_16x16x32_bf16(a[mb][1], b1, acc,  0, 0, 0);
                #pragma unroll
                for (int rr = 0; rr < 4; ++rr) {
                    uint32 kb = (__builtin_bit_cast(uint32, acc[rr]) & 0xFFFFFC00u) | tag;
                    best[mb * 4 + rr] = fmaxf(best[mb * 4 + rr], __builtin_bit_cast(float, kb));
                }
            }
        }

        // cross-lane argmax over the 16 lanes sharing q
        #pragma unroll
        for (int i = 0; i < 16; ++i) {
            float v = best[i];
            #pragma unroll
            for (int d = 1; d < 16; d <<= 1) v = fmaxf(v, __shfl_xor(v, d, 64));
            best[i] = v;
        }
        if (m == 0) {
            #pragma unroll
            for (int mb = 0; mb < 4; ++mb)
                #pragma unroll
                for (int rr = 0; rr < 4; ++rr)
                    partial[ng][mg * 64 + mb * 16 + q * 4 + rr] = best[mb * 4 + rr];
        }
        __syncthreads();

        // ---- writeback: combine n-groups, gather vq from LDS, store + loss ----
        {
            float km = partial[0][r];
            #pragma unroll
            for (int j = 1; j < 8; ++j) km = fmaxf(km, partial[j][r]);
            int idx = 1023 - (int)(__builtin_bit_cast(uint32, km) & 1023u);

            int epos = (idx << 6) + (((cg + idx) & 7) << 3); // this thread's chunk cg
            ushort4v ec0 = *(const ushort4v*)&cbL[epos];
            ushort4v ec1 = *(const ushort4v*)&cbL[epos + 4];
            ushort4v zb0 = *(const ushort4v*)&Abf[r * 72 + cg * 8];
            ushort4v zb1 = *(const ushort4v*)&Abf[r * 72 + cg * 8 + 4];

            float lsum = 0.f;
            #pragma unroll
            for (int j = 0; j < 4; ++j) {
                float v0  = __builtin_bit_cast(float, (uint32)ec0[j] << 16);
                float v1  = __builtin_bit_cast(float, (uint32)ec1[j] << 16);
                float zp0 = __builtin_bit_cast(float, (uint32)zb0[j] << 16);
                float zp1 = __builtin_bit_cast(float, (uint32)zb1[j] << 16);
                out[1 + zoffT + (cg * 8 + j) * HWALL + r]     = v0;   // ST fwd == vq
                out[1 + zoffT + (cg * 8 + 4 + j) * HWALL + r] = v1;
                float d0 = v0 - zp0, d1 = v1 - zp1;
                lsum += d0 * d0 + d1 * d1;
            }
            #pragma unroll
            for (int d = 1; d < 64; d <<= 1) lsum += __shfl_xor(lsum, d, 64);
            if (l == 0) atomicAdd(&loss_acc, lsum);
        }
        __syncthreads();   // Abf reads done; partials reusable

        if (T == 0) {
            // ---- tile-1 z (already in regs) -> Abf ----
            ushort4v pk0, pk1;
            #pragma unroll
            for (int j = 0; j < 4; ++j) { pk0[j] = f2bf(z1v[j]); pk1[j] = f2bf(z1v[4 + j]); }
            *(ushort4v*)&Abf[r * 72 + cg * 8]     = pk0;
            *(ushort4v*)&Abf[r * 72 + cg * 8 + 4] = pk1;
            __syncthreads();
            zoffT += 128;
        }
    }

    if (t == 0) atomicAdd(out, loss_acc * (1.25f / 4194304.f));  // (1+BETA)/numel
}

extern "C" void kernel_launch(void* const* d_in, const int* in_sizes, int n_in,
                              void* d_out, int out_size, void* d_ws, size_t ws_size,
                              hipStream_t stream) {
    (void)in_sizes; (void)n_in; (void)out_size; (void)d_ws; (void)ws_size;
    const float* z  = (const float*)d_in[0];
    const float* cb = (const float*)d_in[1];
    float* out = (float*)d_out;

    hipMemsetAsync(d_out, 0, sizeof(float), stream);   // zero the loss cell
    vq_kernel<<<dim3(256), dim3(1024), 0, stream>>>(z, cb, out);
}

// Round 6
// 90.109 us; speedup vs baseline: 1.0481x; 1.0481x over previous
//
#include <hip/hip_runtime.h>

typedef unsigned int uint32;
typedef unsigned short ushort;

typedef __bf16  bf16x8   __attribute__((ext_vector_type(8)));
typedef float   f32x4    __attribute__((ext_vector_type(4)));
typedef ushort  ushort4v __attribute__((ext_vector_type(4)));

#define K_CODES 1024
#define CDIM    64
#define HWALL   4096      // H*W
#define CHW     262144    // CDIM*HWALL
#define ROWS    128       // z-rows per block

__device__ __forceinline__ ushort f2bf(float f) {
    uint32 u = __builtin_bit_cast(uint32, f);
    u += 0x7FFFu + ((u >> 16) & 1u);   // RNE
    return (ushort)(u >> 16);
}

// Pass 0 (tiny): codebook fp32 -> bf16 row-major + negbias[k] = -0.5*||e_k||^2.
// Also zeroes the loss cell out[0].
__global__ __launch_bounds__(256) void prep_kernel(const float* __restrict__ cb,
                                                   ushort* __restrict__ cbb,
                                                   float* __restrict__ negbias,
                                                   float* __restrict__ out) {
    int t = threadIdx.x;
    if (blockIdx.x == 0 && t == 0) out[0] = 0.f;
    int k = blockIdx.x * 4 + (t >> 6);
    int c = t & 63;
    float v = cb[k * 64 + c];
    cbb[k * 64 + c] = f2bf(v);
    float s = v * v;
    #pragma unroll
    for (int d = 1; d < 64; d <<= 1) s += __shfl_xor(s, d, 64);
    if (c == 0) negbias[k] = -0.5f * s;
}

// Main: 512 blocks x 1024 threads (16 waves), 2 blocks/CU (LDS 26 KB, VGPR<=128).
// CODEBOOK LIVES IN REGISTERS: wave w holds B-fragments for n-tiles [w*4,+4)
// (32 VGPRs) + negbias (4 VGPRs), loaded once per block. Hot loop: A-frags from
// LDS + MFMA + pack only -- zero B loads. Each wave sweeps all 8 m-blocks of the
// block's 128 rows; 16-way argmax combine via LDS partial-key table.
__global__ __launch_bounds__(1024, 4) void vq_kernel(const float* __restrict__ z,
                                                     const ushort* __restrict__ cbb,
                                                     const float* __restrict__ negbias,
                                                     const float* __restrict__ cb,
                                                     float* __restrict__ out) {
    __shared__ __align__(16) ushort Abf[ROWS * 72];   // 18 KB A-tile, pitch 72
    __shared__ float partial[16][ROWS];               // 8 KB packed argmax keys
    __shared__ float loss_acc;

    const int t   = threadIdx.x;
    const int blk = blockIdx.x;
    const int b   = blk >> 5;
    const int hw_base = (blk & 31) << 7;     // 32 groups of 128 rows
    const int zoff = b * CHW + hw_base;

    if (t == 0) loss_acc = 0.f;

    const int r  = t & 127;    // z-row (lanes consecutive -> coalesced 256B)
    const int cg = t >> 7;     // c-group 0..7
    const int w  = t >> 6;     // wave 0..15: owns n-tiles [w*4, +4)
    const int l  = t & 63;
    const int m  = l & 15;     // B col within n-tile / A row within m-block
    const int q  = l >> 4;     // k-quad

    // ---- issue z loads (deepest dep) ----
    float zv[8];
    #pragma unroll
    for (int j = 0; j < 8; ++j) zv[j] = z[zoff + (cg * 8 + j) * HWALL + r];

    // ---- load this wave's codebook slice into registers ----
    bf16x8 Bv[4][2];
    float  nb[4];
    #pragma unroll
    for (int j = 0; j < 4; ++j) {
        int col = (((w << 2) + j) << 4) + m;
        Bv[j][0] = *(const bf16x8*)&cbb[(col << 6) + (q << 3)];
        Bv[j][1] = *(const bf16x8*)&cbb[(col << 6) + 32 + (q << 3)];
        nb[j] = negbias[col];
    }

    // ---- stage z tile -> Abf (bf16, pitch 72) ----
    {
        ushort4v pk0, pk1;
        #pragma unroll
        for (int j = 0; j < 4; ++j) { pk0[j] = f2bf(zv[j]); pk1[j] = f2bf(zv[4 + j]); }
        *(ushort4v*)&Abf[r * 72 + cg * 8]     = pk0;
        *(ushort4v*)&Abf[r * 72 + cg * 8 + 4] = pk1;
    }
    __syncthreads();

    // ---- gemm: sweep all 8 m-blocks x this wave's 4 n-tiles ----
    float best[32];
    #pragma unroll
    for (int i = 0; i < 32; ++i) best[i] = -__builtin_inff();

    #pragma unroll
    for (int mb = 0; mb < 8; ++mb) {
        bf16x8 a0 = *(const bf16x8*)&Abf[(mb * 16 + m) * 72 + (q << 3)];
        bf16x8 a1 = *(const bf16x8*)&Abf[(mb * 16 + m) * 72 + 32 + (q << 3)];
        #pragma unroll
        for (int j = 0; j < 4; ++j) {
            uint32 tag = 1023u - (uint32)(((((w << 2) + j) << 4)) + m);
            f32x4 acc0;
            acc0[0] = nb[j]; acc0[1] = nb[j]; acc0[2] = nb[j]; acc0[3] = nb[j];
            f32x4 acc = __builtin_amdgcn_mfma_f32_16x16x32_bf16(a0, Bv[j][0], acc0, 0, 0, 0);
            acc       = __builtin_amdgcn_mfma_f32_16x16x32_bf16(a1, Bv[j][1], acc,  0, 0, 0);
            #pragma unroll
            for (int rr = 0; rr < 4; ++rr) {
                uint32 kb = (__builtin_bit_cast(uint32, acc[rr]) & 0xFFFFFC00u) | tag;
                best[mb * 4 + rr] = fmaxf(best[mb * 4 + rr], __builtin_bit_cast(float, kb));
            }
        }
    }

    // cross-lane argmax over the 16 cols (lanes sharing q)
    #pragma unroll
    for (int i = 0; i < 32; ++i) {
        float v = best[i];
        #pragma unroll
        for (int d = 1; d < 16; d <<= 1) v = fmaxf(v, __shfl_xor(v, d, 64));
        best[i] = v;
    }
    if (m == 0) {     // lanes q=0..3: rows mb*16 + q*4 + rr
        #pragma unroll
        for (int mb = 0; mb < 8; ++mb)
            #pragma unroll
            for (int rr = 0; rr < 4; ++rr)
                partial[w][mb * 16 + (q << 2) + rr] = best[mb * 4 + rr];
    }
    __syncthreads();

    // ---- writeback: 16-way combine, gather vq from L2-resident fp32 cb ----
    {
        float km = partial[0][r];
        #pragma unroll
        for (int j = 1; j < 16; ++j) km = fmaxf(km, partial[j][r]);
        int idx = 1023 - (int)(__builtin_bit_cast(uint32, km) & 1023u);

        const f32x4* crow = (const f32x4*)(cb + (idx << 6) + (cg << 3));
        f32x4 e0 = crow[0];
        f32x4 e1 = crow[1];
        ushort4v zb0 = *(const ushort4v*)&Abf[r * 72 + cg * 8];
        ushort4v zb1 = *(const ushort4v*)&Abf[r * 72 + cg * 8 + 4];

        float lsum = 0.f;
        #pragma unroll
        for (int j = 0; j < 4; ++j) {
            float v0  = e0[j];
            float v1  = e1[j];
            float zp0 = __builtin_bit_cast(float, (uint32)zb0[j] << 16);
            float zp1 = __builtin_bit_cast(float, (uint32)zb1[j] << 16);
            out[1 + zoff + (cg * 8 + j) * HWALL + r]     = v0;   // ST fwd == vq
            out[1 + zoff + (cg * 8 + 4 + j) * HWALL + r] = v1;
            float d0 = v0 - zp0, d1 = v1 - zp1;
            lsum += d0 * d0 + d1 * d1;
        }
        #pragma unroll
        for (int d = 1; d < 64; d <<= 1) lsum += __shfl_xor(lsum, d, 64);
        if (l == 0) atomicAdd(&loss_acc, lsum);
    }
    __syncthreads();
    if (t == 0) atomicAdd(out, loss_acc * (1.25f / 4194304.f));  // (1+BETA)/numel
}

extern "C" void kernel_launch(void* const* d_in, const int* in_sizes, int n_in,
                              void* d_out, int out_size, void* d_ws, size_t ws_size,
                              hipStream_t stream) {
    (void)in_sizes; (void)n_in; (void)out_size; (void)ws_size;
    const float* z  = (const float*)d_in[0];
    const float* cb = (const float*)d_in[1];
    float* out = (float*)d_out;
    ushort* cbb = (ushort*)d_ws;
    float* negbias = (float*)((char*)d_ws + K_CODES * CDIM * sizeof(ushort));

    prep_kernel<<<dim3(256), dim3(256), 0, stream>>>(cb, cbb, negbias, out);
    vq_kernel<<<dim3(512), dim3(1024), 0, stream>>>(z, cbb, negbias, cb, out);
}